// Round 4
// baseline (88.723 us; speedup 1.0000x reference)
//
#include <hip/hip_runtime.h>
#include <hip/hip_bf16.h>

// x:      (8, 3, 512, 512) fp32
// shift:  (16, 3) fp32
// slopes: (16, 3) fp32
// conv_w: (3,)  fp32
// conv_b: (1,)  fp32
// out:    (8, 1, 512, 512) fp32
//
// out[b,h,w] = clip( conv_b + sum_c conv_w[c] * sum_p slopes[p,c]*relu(x[b,c,h,w]-shift[p,c]), 0, 1 )
//
// Memory-bound: 25.2 MB read + 8.4 MB write => ~5.3 us floor @ 6.3 TB/s.
// Two float4 groups per thread (6 coalesced loads in flight), nontemporal
// loads/stores (streaming data, touched once). Nontemporal builtins need a
// native clang vector type, not HIP_vector_type -> use ext_vector_type(4).

typedef float f32x4 __attribute__((ext_vector_type(4)));

constexpr int NPTS = 16;
constexpr int C    = 3;
constexpr int HW   = 512 * 512;   // 2^18
constexpr int HW4  = HW / 4;      // 65536 = 2^16  (float4 per (b,c) plane)

__device__ __forceinline__ void pwl_accum(const f32x4 xv,
                                          const float* __restrict__ shift,
                                          const float* __restrict__ slopes,
                                          const int c, const float w,
                                          float& ax, float& ay, float& az, float& aw)
{
    float yx = 0.f, yy = 0.f, yz = 0.f, yw = 0.f;
#pragma unroll
    for (int p = 0; p < NPTS; ++p) {
        const float s = shift[p * C + c];    // wave-uniform -> SGPR
        const float m = slopes[p * C + c];
        yx += m * fmaxf(xv.x - s, 0.f);
        yy += m * fmaxf(xv.y - s, 0.f);
        yz += m * fmaxf(xv.z - s, 0.f);
        yw += m * fmaxf(xv.w - s, 0.f);
    }
    ax += w * yx; ay += w * yy; az += w * yz; aw += w * yw;
}

__device__ __forceinline__ f32x4 clamp01(float ax, float ay, float az, float aw)
{
    f32x4 o;
    o.x = fminf(fmaxf(ax, 0.f), 1.f);
    o.y = fminf(fmaxf(ay, 0.f), 1.f);
    o.z = fminf(fmaxf(az, 0.f), 1.f);
    o.w = fminf(fmaxf(aw, 0.f), 1.f);
    return o;
}

__global__ __launch_bounds__(256)
void curve_channel_kernel(const f32x4* __restrict__ x,
                          const float* __restrict__ shift,   // (NPTS, C)
                          const float* __restrict__ slopes,  // (NPTS, C)
                          const float* __restrict__ conv_w,  // (C,)
                          const float* __restrict__ conv_b,  // (1,)
                          f32x4*       __restrict__ out,
                          int n4)
{
    // Each block covers 512 consecutive float4s; each thread takes tid, tid+256.
    const int i0 = blockIdx.x * 512 + threadIdx.x;
    const int i1 = i0 + 256;

    const float bias = conv_b[0];
    const float w0 = conv_w[0], w1 = conv_w[1], w2 = conv_w[2];

    if (i1 < n4) {
        const int b  = i0 >> 16;             // same batch for i0 and i1 (512 | 65536)
        const int h0 = i0 & (HW4 - 1);
        const int h1 = i1 & (HW4 - 1);
        const f32x4* xb = x + (size_t)b * (C * HW4);

        // issue all 6 loads up front (coalesced, nontemporal)
        const f32x4 a0 = __builtin_nontemporal_load(xb + 0 * HW4 + h0);
        const f32x4 a1 = __builtin_nontemporal_load(xb + 0 * HW4 + h1);
        const f32x4 b0 = __builtin_nontemporal_load(xb + 1 * HW4 + h0);
        const f32x4 b1 = __builtin_nontemporal_load(xb + 1 * HW4 + h1);
        const f32x4 c0 = __builtin_nontemporal_load(xb + 2 * HW4 + h0);
        const f32x4 c1 = __builtin_nontemporal_load(xb + 2 * HW4 + h1);

        float px = bias, py = bias, pz = bias, pw = bias;
        float qx = bias, qy = bias, qz = bias, qw = bias;
        pwl_accum(a0, shift, slopes, 0, w0, px, py, pz, pw);
        pwl_accum(a1, shift, slopes, 0, w0, qx, qy, qz, qw);
        pwl_accum(b0, shift, slopes, 1, w1, px, py, pz, pw);
        pwl_accum(b1, shift, slopes, 1, w1, qx, qy, qz, qw);
        pwl_accum(c0, shift, slopes, 2, w2, px, py, pz, pw);
        pwl_accum(c1, shift, slopes, 2, w2, qx, qy, qz, qw);

        __builtin_nontemporal_store(clamp01(px, py, pz, pw), out + i0);
        __builtin_nontemporal_store(clamp01(qx, qy, qz, qw), out + i1);
    } else {
        // tail (not hit for the reference shape; kept for robustness)
        for (int i = i0; i < n4; i += 256) {
            const int b = i >> 16;
            const int h = i & (HW4 - 1);
            const f32x4* xb = x + (size_t)b * (C * HW4);
            float px = bias, py = bias, pz = bias, pw = bias;
            pwl_accum(xb[0 * HW4 + h], shift, slopes, 0, w0, px, py, pz, pw);
            pwl_accum(xb[1 * HW4 + h], shift, slopes, 1, w1, px, py, pz, pw);
            pwl_accum(xb[2 * HW4 + h], shift, slopes, 2, w2, px, py, pz, pw);
            out[i] = clamp01(px, py, pz, pw);
        }
    }
}

extern "C" void kernel_launch(void* const* d_in, const int* in_sizes, int n_in,
                              void* d_out, int out_size, void* d_ws, size_t ws_size,
                              hipStream_t stream)
{
    const float* x      = (const float*)d_in[0];
    const float* shift  = (const float*)d_in[1];
    const float* slopes = (const float*)d_in[2];
    const float* conv_w = (const float*)d_in[3];
    const float* conv_b = (const float*)d_in[4];
    float*       out    = (float*)d_out;

    const int n4     = out_size / 4;            // float4 outputs
    const int blocks = (n4 + 511) / 512;        // 512 float4s per block

    curve_channel_kernel<<<dim3(blocks), dim3(256), 0, stream>>>(
        (const f32x4*)x, shift, slopes, conv_w, conv_b, (f32x4*)out, n4);
}

// Round 5
// 84.813 us; speedup vs baseline: 1.0461x; 1.0461x over previous
//
#include <hip/hip_runtime.h>
#include <hip/hip_bf16.h>

// x:      (8, 3, 512, 512) fp32
// shift:  (16, 3) fp32
// slopes: (16, 3) fp32
// conv_w: (3,)  fp32
// conv_b: (1,)  fp32
// out:    (8, 1, 512, 512) fp32
//
// out[b,h,w] = clip( conv_b + sum_c conv_w[c] * sum_p slopes[p,c]*relu(x[b,c,h,w]-shift[p,c]), 0, 1 )
//
// Memory-bound fused elementwise. NOTE: the harness restores x via d2d copy
// right before the timed launch, so x is Infinity-Cache-warm -> use normal
// cached loads/stores (nontemporal hints measurably regressed: 80.4->88.7us).
// Two float4 groups per thread, all 6 loads issued up front for ILP.

typedef float f32x4 __attribute__((ext_vector_type(4)));

constexpr int NPTS = 16;
constexpr int C    = 3;
constexpr int HW   = 512 * 512;   // 2^18
constexpr int HW4  = HW / 4;      // 65536 = 2^16  (float4 per (b,c) plane)

__device__ __forceinline__ void pwl_accum(const f32x4 xv,
                                          const float* __restrict__ shift,
                                          const float* __restrict__ slopes,
                                          const int c, const float w,
                                          float& ax, float& ay, float& az, float& aw)
{
    float yx = 0.f, yy = 0.f, yz = 0.f, yw = 0.f;
#pragma unroll
    for (int p = 0; p < NPTS; ++p) {
        const float s = shift[p * C + c];    // wave-uniform -> SGPR
        const float m = slopes[p * C + c];
        yx += m * fmaxf(xv.x - s, 0.f);
        yy += m * fmaxf(xv.y - s, 0.f);
        yz += m * fmaxf(xv.z - s, 0.f);
        yw += m * fmaxf(xv.w - s, 0.f);
    }
    ax += w * yx; ay += w * yy; az += w * yz; aw += w * yw;
}

__device__ __forceinline__ f32x4 clamp01(float ax, float ay, float az, float aw)
{
    f32x4 o;
    o.x = fminf(fmaxf(ax, 0.f), 1.f);
    o.y = fminf(fmaxf(ay, 0.f), 1.f);
    o.z = fminf(fmaxf(az, 0.f), 1.f);
    o.w = fminf(fmaxf(aw, 0.f), 1.f);
    return o;
}

__global__ __launch_bounds__(256)
void curve_channel_kernel(const f32x4* __restrict__ x,
                          const float* __restrict__ shift,   // (NPTS, C)
                          const float* __restrict__ slopes,  // (NPTS, C)
                          const float* __restrict__ conv_w,  // (C,)
                          const float* __restrict__ conv_b,  // (1,)
                          f32x4*       __restrict__ out,
                          int n4)
{
    // Each block covers 512 consecutive float4s; each thread takes tid, tid+256.
    const int i0 = blockIdx.x * 512 + threadIdx.x;
    const int i1 = i0 + 256;

    const float bias = conv_b[0];
    const float w0 = conv_w[0], w1 = conv_w[1], w2 = conv_w[2];

    if (i1 < n4) {
        const int b  = i0 >> 16;             // same batch for i0 and i1 (512 | 65536)
        const int h0 = i0 & (HW4 - 1);
        const int h1 = i1 & (HW4 - 1);
        const f32x4* xb = x + (size_t)b * (C * HW4);

        // issue all 6 loads up front (coalesced, cached)
        const f32x4 a0 = xb[0 * HW4 + h0];
        const f32x4 a1 = xb[0 * HW4 + h1];
        const f32x4 b0 = xb[1 * HW4 + h0];
        const f32x4 b1 = xb[1 * HW4 + h1];
        const f32x4 c0 = xb[2 * HW4 + h0];
        const f32x4 c1 = xb[2 * HW4 + h1];

        float px = bias, py = bias, pz = bias, pw = bias;
        float qx = bias, qy = bias, qz = bias, qw = bias;
        pwl_accum(a0, shift, slopes, 0, w0, px, py, pz, pw);
        pwl_accum(a1, shift, slopes, 0, w0, qx, qy, qz, qw);
        pwl_accum(b0, shift, slopes, 1, w1, px, py, pz, pw);
        pwl_accum(b1, shift, slopes, 1, w1, qx, qy, qz, qw);
        pwl_accum(c0, shift, slopes, 2, w2, px, py, pz, pw);
        pwl_accum(c1, shift, slopes, 2, w2, qx, qy, qz, qw);

        out[i0] = clamp01(px, py, pz, pw);
        out[i1] = clamp01(qx, qy, qz, qw);
    } else {
        // tail (not hit for the reference shape; kept for robustness)
        for (int i = i0; i < n4; i += 256) {
            const int b = i >> 16;
            const int h = i & (HW4 - 1);
            const f32x4* xb = x + (size_t)b * (C * HW4);
            float px = bias, py = bias, pz = bias, pw = bias;
            pwl_accum(xb[0 * HW4 + h], shift, slopes, 0, w0, px, py, pz, pw);
            pwl_accum(xb[1 * HW4 + h], shift, slopes, 1, w1, px, py, pz, pw);
            pwl_accum(xb[2 * HW4 + h], shift, slopes, 2, w2, px, py, pz, pw);
            out[i] = clamp01(px, py, pz, pw);
        }
    }
}

extern "C" void kernel_launch(void* const* d_in, const int* in_sizes, int n_in,
                              void* d_out, int out_size, void* d_ws, size_t ws_size,
                              hipStream_t stream)
{
    const float* x      = (const float*)d_in[0];
    const float* shift  = (const float*)d_in[1];
    const float* slopes = (const float*)d_in[2];
    const float* conv_w = (const float*)d_in[3];
    const float* conv_b = (const float*)d_in[4];
    float*       out    = (float*)d_out;

    const int n4     = out_size / 4;            // float4 outputs
    const int blocks = (n4 + 511) / 512;        // 512 float4s per block

    curve_channel_kernel<<<dim3(blocks), dim3(256), 0, stream>>>(
        (const f32x4*)x, shift, slopes, conv_w, conv_b, (f32x4*)out, n4);
}

// Round 6
// 81.211 us; speedup vs baseline: 1.0925x; 1.0444x over previous
//
#include <hip/hip_runtime.h>
#include <hip/hip_bf16.h>

// x:      (8, 3, 512, 512) fp32
// shift:  (16, 3) fp32
// slopes: (16, 3) fp32
// conv_w: (3,)  fp32
// conv_b: (1,)  fp32
// out:    (8, 1, 512, 512) fp32
//
// out[b,h,w] = clip( conv_b + sum_c conv_w[c] * sum_p slopes[p,c]*relu(x[b,c,h,w]-shift[p,c]), 0, 1 )
//
// Memory-bound fused elementwise: 25.2 MB read + 8.4 MB write -> ~5.3 us
// floor @ 6.3 TB/s. Measured A/B: 1 float4/thread cached (80.4us total incl.
// ~70us harness fixed cost) beats 2 float4/thread cached (84.8) and NT (88.7)
// -- x is L3-warm from the harness's pre-launch restore, and 8 waves/SIMD
// already hides latency, so the simplest structure wins. This is that kernel.

constexpr int NPTS = 16;
constexpr int C    = 3;
constexpr int HW   = 512 * 512;   // 262144 = 2^18
constexpr int HW4  = HW / 4;      // 65536 = 2^16

__global__ __launch_bounds__(256)
void curve_channel_kernel(const float4* __restrict__ x,
                          const float*  __restrict__ shift,   // (NPTS, C)
                          const float*  __restrict__ slopes,  // (NPTS, C)
                          const float*  __restrict__ conv_w,  // (C,)
                          const float*  __restrict__ conv_b,  // (1,)
                          float4*       __restrict__ out,
                          int n4)                              // total float4 outputs
{
    const int idx = blockIdx.x * 256 + threadIdx.x;   // float4 index in [0, n4)
    if (idx >= n4) return;

    const int b   = idx >> 16;                        // idx / HW4  (HW4 = 2^16)
    const int hw4 = idx & (HW4 - 1);                  // idx % HW4

    const float4* xb = x + (size_t)b * (C * HW4) + hw4;

    const float bias = conv_b[0];
    float ax = bias, ay = bias, az = bias, aw = bias;

#pragma unroll
    for (int c = 0; c < C; ++c) {
        const float4 xv = xb[(size_t)c * HW4];
        const float  w  = conv_w[c];
        float yx = 0.f, yy = 0.f, yz = 0.f, yw = 0.f;
#pragma unroll
        for (int p = 0; p < NPTS; ++p) {
            const float s = shift[p * C + c];   // wave-uniform -> scalar load
            const float m = slopes[p * C + c];
            yx += m * fmaxf(xv.x - s, 0.f);
            yy += m * fmaxf(xv.y - s, 0.f);
            yz += m * fmaxf(xv.z - s, 0.f);
            yw += m * fmaxf(xv.w - s, 0.f);
        }
        ax += w * yx;
        ay += w * yy;
        az += w * yz;
        aw += w * yw;
    }

    float4 o;
    o.x = fminf(fmaxf(ax, 0.f), 1.f);
    o.y = fminf(fmaxf(ay, 0.f), 1.f);
    o.z = fminf(fmaxf(az, 0.f), 1.f);
    o.w = fminf(fmaxf(aw, 0.f), 1.f);
    out[idx] = o;
}

extern "C" void kernel_launch(void* const* d_in, const int* in_sizes, int n_in,
                              void* d_out, int out_size, void* d_ws, size_t ws_size,
                              hipStream_t stream)
{
    const float* x      = (const float*)d_in[0];
    const float* shift  = (const float*)d_in[1];
    const float* slopes = (const float*)d_in[2];
    const float* conv_w = (const float*)d_in[3];
    const float* conv_b = (const float*)d_in[4];
    float*       out    = (float*)d_out;

    const int n4     = out_size / 4;              // float4 outputs
    const int blocks = (n4 + 255) / 256;

    curve_channel_kernel<<<dim3(blocks), dim3(256), 0, stream>>>(
        (const float4*)x, shift, slopes, conv_w, conv_b, (float4*)out, n4);
}